// Round 10
// baseline (104.651 us; speedup 1.0000x reference)
//
#include <hip/hip_runtime.h>
#include <math.h>

#define NQ 20
#define OUT_DIM 512
#define FAN_IN 21     // QOUT + COND_DIM
#define BATCH 262144
#define GRID 2048     // each block owns 128 contiguous rows
#define CHUNK (BATCH / GRID)       // 128
#define WFLOATS (OUT_DIM * FAN_IN) // 10752 floats = 43 KB

typedef float vfloat4 __attribute__((ext_vector_type(4)));

// ---------------------------------------------------------------------------
// Single fused kernel (R9 structure). Single change vs R9: the per-iteration
// LDS cond read is replaced by a register preload of all 64 cond values per
// thread (16 uniform float4 loads), and the store loop is FULLY UNROLLED so
// cv[] stays in registers (runtime-indexed ext_vector arrays go to scratch).
// Halves now cover contiguous row ranges: half 0 -> rows 0..63 of the chunk,
// half 1 -> rows 64..127, so each thread's cond values are contiguous.
//
//   qout[w] = cos(p0[w])cos(p1[w]) - sin(p0[w])sin(p1[w])*CL*CR   (closed
//     form; trailing CZ layer is diagonal -> no effect on probabilities)
//   B2[j] = 2*log2e*(b[j] + qout.W[j,:20]);  A2[j] = 2*log2e*W[j,20]
//   out[i][j] = 1 - 2/(2^(fma(c_i,A2_j,B2_j)) + 1)        ( = tanh )
// ---------------------------------------------------------------------------
__global__ __launch_bounds__(256)
void fused_kernel(const float* __restrict__ cond,
                  const float* __restrict__ params,
                  const float* __restrict__ W,
                  const float* __restrict__ b,
                  float* __restrict__ out)
{
    __shared__ float sW[WFLOATS];   // 43 KB, coalesced-staged copy of W
    __shared__ float qout[NQ];

    const int t    = threadIdx.x;
    const int blk  = blockIdx.x;
    const int half = t >> 7;            // 0: rows 0..63, 1: rows 64..127
    const int j    = (t & 127) << 2;    // column quad

    // stage W coalesced: 2688 float4s over 256 threads
    {
        const vfloat4* Wv = reinterpret_cast<const vfloat4*>(W);
        vfloat4* sWv = reinterpret_cast<vfloat4*>(sW);
        for (int i = t; i < WFLOATS / 4; i += 256) sWv[i] = Wv[i];
    }

    // closed-form circuit output (threads 0..19)
    if (t < NQ) {
        float p0 = params[t];
        float p1 = params[NQ + t];
        float cl = (t > 0)      ? cosf(params[t - 1]) : 1.0f;
        float cr = (t < NQ - 1) ? cosf(params[t + 1]) : 1.0f;
        qout[t] = cosf(p0) * cosf(p1) - sinf(p0) * sinf(p1) * cl * cr;
    }

    const vfloat4 bb = *reinterpret_cast<const vfloat4*>(b + j);  // coalesced
    __syncthreads();

    // preload this thread's 64 cond values (wave-uniform addresses ->
    // L1 cacheline broadcast); issue before the LDS dot so latency hides.
    const float* cbase = cond + blk * CHUNK + half * 64;
    vfloat4 cv[16];
#pragma unroll
    for (int i = 0; i < 16; ++i)
        cv[i] = *reinterpret_cast<const vfloat4*>(cbase + 4 * i);

    // per-thread prep from LDS: A = 2*log2e*wlast, B = 2*log2e*base
    const float TWO_LOG2E = 2.8853900817779268f;
    vfloat4 A, B;
#pragma unroll
    for (int r = 0; r < 4; ++r) {
        const float* wr = sW + (j + r) * FAN_IN;
        float acc = bb[r];
#pragma unroll
        for (int k = 0; k < NQ; ++k) acc += qout[k] * wr[k];
        B[r] = TWO_LOG2E * acc;
        A[r] = TWO_LOG2E * wr[NQ];
    }

    float* p = out + (size_t)(blk * CHUNK + half * 64) * OUT_DIM + j;

    // fully unrolled store loop: all cv indices compile-time constant
#pragma unroll
    for (int i = 0; i < 16; ++i) {
#pragma unroll
        for (int k = 0; k < 4; ++k) {
            const float c = cv[i][k];
            vfloat4 o;
#pragma unroll
            for (int q = 0; q < 4; ++q) {
                float e = __builtin_amdgcn_exp2f(fmaf(c, A[q], B[q]));
                o[q] = fmaf(-2.0f, __builtin_amdgcn_rcpf(e + 1.0f), 1.0f);
            }
            *reinterpret_cast<vfloat4*>(p) = o;
            p += OUT_DIM;               // next row
        }
    }
}

extern "C" void kernel_launch(void* const* d_in, const int* in_sizes, int n_in,
                              void* d_out, int out_size, void* d_ws, size_t ws_size,
                              hipStream_t stream)
{
    const float* cond   = (const float*)d_in[0];  // (BATCH, 1)
    const float* params = (const float*)d_in[1];  // (2, NQ)
    const float* W      = (const float*)d_in[2];  // (OUT_DIM, FAN_IN)
    const float* b      = (const float*)d_in[3];  // (OUT_DIM,)
    float* out = (float*)d_out;

    fused_kernel<<<GRID, 256, 0, stream>>>(cond, params, W, b, out);
}

// Round 11
// 98.681 us; speedup vs baseline: 1.0605x; 1.0605x over previous
//
#include <hip/hip_runtime.h>
#include <math.h>

#define NQ 20
#define OUT_DIM 512
#define FAN_IN 21     // QOUT + COND_DIM
#define BATCH 262144
#define GRID 2048     // each block owns 128 contiguous rows (256 KiB stream)
#define CHUNK (BATCH / GRID)       // 128
#define WFLOATS (OUT_DIM * FAN_IN) // 10752 floats = 43 KB

typedef float vfloat4 __attribute__((ext_vector_type(4)));

// ---------------------------------------------------------------------------
// Best-measured kernel (R9, 98.9 us): single fused kernel, R5 store
// structure + in-block prep with COALESCED W staging through LDS.
//
//   qout[w] = cos(p0[w])cos(p1[w]) - sin(p0[w])sin(p1[w])*CL*CR   (closed
//     form; trailing CZ layer is diagonal -> no effect on probabilities)
//   B2[j] = 2*log2e*(b[j] + qout.W[j,:20]);  A2[j] = 2*log2e*W[j,20]
//   out[i][j] = 1 - 2/(2^(fma(c_i,A2_j,B2_j)) + 1)        ( = tanh )
//
// Probes ruled out (falsified): chip-wide marching stores, nontemporal
// stores, 1024-stream layout, cond-in-VGPR unrolled loop. The per-iter
// LDS cond broadcast + plain float4 stores + 2048 private 256 KiB
// streams is the measured optimum.
// ---------------------------------------------------------------------------
__global__ __launch_bounds__(256)
void fused_kernel(const float* __restrict__ cond,
                  const float* __restrict__ params,
                  const float* __restrict__ W,
                  const float* __restrict__ b,
                  float* __restrict__ out)
{
    __shared__ float sW[WFLOATS];   // 43 KB, coalesced-staged copy of W
    __shared__ float qout[NQ];
    __shared__ float sc[CHUNK];

    const int t    = threadIdx.x;
    const int blk  = blockIdx.x;
    const int half = t >> 7;            // which row of each pair
    const int j    = (t & 127) << 2;    // column quad

    // stage cond rows (coalesced 512 B)
    if (t < CHUNK) sc[t] = cond[blk * CHUNK + t];

    // stage W coalesced: 2688 float4s over 256 threads
    {
        const vfloat4* Wv = reinterpret_cast<const vfloat4*>(W);
        vfloat4* sWv = reinterpret_cast<vfloat4*>(sW);
        for (int i = t; i < WFLOATS / 4; i += 256) sWv[i] = Wv[i];
    }

    // closed-form circuit output (threads 0..19)
    if (t < NQ) {
        float p0 = params[t];
        float p1 = params[NQ + t];
        float cl = (t > 0)      ? cosf(params[t - 1]) : 1.0f;
        float cr = (t < NQ - 1) ? cosf(params[t + 1]) : 1.0f;
        qout[t] = cosf(p0) * cosf(p1) - sinf(p0) * sinf(p1) * cl * cr;
    }

    const vfloat4 bb = *reinterpret_cast<const vfloat4*>(b + j);  // coalesced
    __syncthreads();

    // per-thread prep from LDS: A = 2*log2e*wlast, B = 2*log2e*base
    const float TWO_LOG2E = 2.8853900817779268f;
    vfloat4 A, B;
#pragma unroll
    for (int r = 0; r < 4; ++r) {
        const float* wr = sW + (j + r) * FAN_IN;
        float acc = bb[r];
#pragma unroll
        for (int k = 0; k < NQ; ++k) acc += qout[k] * wr[k];
        B[r] = TWO_LOG2E * acc;
        A[r] = TWO_LOG2E * wr[NQ];
    }

    float* p = out + (size_t)(blk * CHUNK + half) * OUT_DIM + j;

#pragma unroll 8
    for (int r = 0; r < CHUNK / 2; ++r) {
        const float c = sc[2 * r + half];   // LDS broadcast
        vfloat4 o;
#pragma unroll
        for (int q = 0; q < 4; ++q) {
            float e = __builtin_amdgcn_exp2f(fmaf(c, A[q], B[q]));  // e^{2x}
            o[q] = fmaf(-2.0f, __builtin_amdgcn_rcpf(e + 1.0f), 1.0f);
        }
        *reinterpret_cast<vfloat4*>(p) = o;
        p += 2 * OUT_DIM;                   // advance 2 rows
    }
}

extern "C" void kernel_launch(void* const* d_in, const int* in_sizes, int n_in,
                              void* d_out, int out_size, void* d_ws, size_t ws_size,
                              hipStream_t stream)
{
    const float* cond   = (const float*)d_in[0];  // (BATCH, 1)
    const float* params = (const float*)d_in[1];  // (2, NQ)
    const float* W      = (const float*)d_in[2];  // (OUT_DIM, FAN_IN)
    const float* b      = (const float*)d_in[3];  // (OUT_DIM,)
    float* out = (float*)d_out;

    fused_kernel<<<GRID, 256, 0, stream>>>(cond, params, W, b, out);
}